// Round 1
// 311.907 us; speedup vs baseline: 1.1316x; 1.1316x over previous
//
#include <hip/hip_runtime.h>
#include <hip/hip_bf16.h>

typedef unsigned short u16;
typedef unsigned int u32;
typedef short bf16x8 __attribute__((ext_vector_type(8)));
typedef float f32x4 __attribute__((ext_vector_type(4)));

#define EPSV 1e-5f
// ws byte layout
#define WS_A3    0                       // 128*8 f32
#define WS_C3    4096                    // 128 f32
#define WS_WB    4608                    // 128*128 bf16
#define WS_WCAT  37376                   // 128*160 bf16 [wf2 | A1 | bias | 0]
#define WS_Q     78336                   // 33.55 MB bf16 q = A3@x
#define WS_QD    (78336 + 33554432)      // 33.55 MB bf16 qD = c3 - q
#define WS_NE    (78336 + 2*33554432)    // 33.55 MB bf16 NE

union U4 { uint4 q; bf16x8 v; };

__device__ __forceinline__ u16 f2bf(float f) {
    union { __hip_bfloat16 h; u16 u; } cv;
    cv.h = __float2bfloat16(f);
    return cv.u;
}
__device__ __forceinline__ u32 pack_rne(float a, float b) {
    u32 ua = __float_as_uint(a), ub = __float_as_uint(b);
    ua = ua + 0x7FFFu + ((ua >> 16) & 1u);
    ub = ub + 0x7FFFu + ((ub >> 16) & 1u);
    return (ua >> 16) | (ub & 0xFFFF0000u);
}
// z = relu(bf(a_half) + bf(d_half)), packed bf16 (round-half-up + v_perm)
__device__ __forceinline__ u32 zpair(u32 a, u32 d) {
    float lo = __uint_as_float(a << 16) + __uint_as_float(d << 16);
    float hi = __uint_as_float(a & 0xFFFF0000u) + __uint_as_float(d & 0xFFFF0000u);
    lo = fmaxf(lo, 0.f);
    hi = fmaxf(hi, 0.f);
    return __builtin_amdgcn_perm(__float_as_uint(hi) + 0x8000u,
                                 __float_as_uint(lo) + 0x8000u, 0x07060302u);
}

// ---------------- prep: fold constants (fully parallel, LDS-staged) ----------------
__global__ __launch_bounds__(256) void prep_kernel(
    const float* g1, const float* b1, const float* m1, const float* v1,
    const float* w1, const float* c1b,
    const float* g2, const float* b2, const float* m2, const float* v2,
    const float* wA,
    const float* g3, const float* b3, const float* m3, const float* v3,
    const float* wB, const float* wf, const float* bfv,
    float* ws, u16* wBh, u16* Wc)
{
    __shared__ float wfL[16384];     // wf left half, 64 KB
    __shared__ float w1s[1024];
    __shared__ float c1s[128];
    __shared__ float s1[8], be1[8], s2[8], be2[8];
    __shared__ float w1fS[128][8];
    __shared__ float cbS[128];
    int t = threadIdx.x;

    // stage (coalesced, latency-pipelined across 256 threads)
    for (int i = t; i < 16384; i += 256) wfL[i] = wf[((i >> 7) << 8) + (i & 127)];
    for (int i = t; i < 1024; i += 256) w1s[i] = w1[i];
    if (t < 128) c1s[t] = c1b[t];
    if (t < 8) {
        float s = g1[t] * rsqrtf(v1[t] + EPSV); s1[t] = s; be1[t] = b1[t] - m1[t] * s;
        float u = g2[t] * rsqrtf(v2[t] + EPSV); s2[t] = u; be2[t] = b2[t] - m2[t] * u;
    }
    __syncthreads();

    // fold wf_left @ [w1 | c1b]: thread (o, half) does 4 i's (+ cb on half 1)
    {
        int o = t >> 1, half = t & 1;
        float a0 = 0.f, a1 = 0.f, a2 = 0.f, a3 = 0.f, cb = 0.f;
        const float* wro = wfL + o * 128;
        int i0 = half * 4;
        for (int c = 0; c < 128; c++) {
            float f = wro[c];
            const float* wr = w1s + c * 8 + i0;
            a0 += f * wr[0]; a1 += f * wr[1]; a2 += f * wr[2]; a3 += f * wr[3];
            if (half) cb += f * c1s[c];
        }
        w1fS[o][i0] = a0; w1fS[o][i0 + 1] = a1; w1fS[o][i0 + 2] = a2; w1fS[o][i0 + 3] = a3;
        if (half) cbS[o] = cb;
    }
    __syncthreads();

    if (t < 128) {
        int o = t;
        float s3 = g3[o] * rsqrtf(v3[o] + EPSV);
        float be3 = b3[o] - m3[o] * s3;
        float* A3 = ws;
        float* c3 = ws + 1024;
        float csum = 0.f;
        #pragma unroll
        for (int i = 0; i < 8; i++) {
            float w = wA[o * 8 + i];
            A3[o * 8 + i] = s3 * w * s2[i] * s1[i];
            csum += w * be2[i];
        }
        c3[o] = s3 * csum + be3;

        float bs = bfv[o] + cbS[o];
        #pragma unroll
        for (int i = 0; i < 8; i++) {
            float w1f = w1fS[o][i];
            bs += w1f * be1[i];
            Wc[o * 160 + 128 + i] = f2bf(w1f * s1[i]);
        }
        Wc[o * 160 + 136] = f2bf(bs);
        for (int k = 137; k < 160; k++) Wc[o * 160 + k] = 0;
    }
    // Wcat wf2 block: 16384 elems, coalesced grid-stride
    for (int j = t; j < 16384; j += 256) {
        int o = j >> 7, c = j & 127;
        Wc[o * 160 + c] = f2bf(wf[o * 256 + 128 + c]);
    }
    // wB cast: 8192 packed u32, coalesced
    {
        u32* wbo = (u32*)wBh;
        for (int j = t; j < 8192; j += 256)
            wbo[j] = pack_rne(wB[2 * j], wB[2 * j + 1]);
    }
}

// ---------------- q = A3 @ x (bf16) and qD = c3 - q (bf16) --------------------
__global__ __launch_bounds__(256) void q_kernel(const float* __restrict__ x,
                                                const float* __restrict__ ws,
                                                u16* __restrict__ q,
                                                u16* __restrict__ qD)
{
    int t = blockIdx.x * 256 + threadIdx.x;
    int pt = t >> 6;
    int o = (t & 63) * 2;
    int b = pt >> 16, n = pt & 65535;
    const float* A3 = ws;
    float xv[8];
    #pragma unroll
    for (int i = 0; i < 8; i++) xv[i] = x[(((b << 3) + i) << 16) | n];
    float q0 = 0.f, q1 = 0.f;
    #pragma unroll
    for (int i = 0; i < 8; i++) {
        q0 += A3[o * 8 + i] * xv[i];
        q1 += A3[(o + 1) * 8 + i] * xv[i];
    }
    ((u32*)q)[t] = pack_rne(q0, q1);
    float c0 = ws[1024 + o], c1 = ws[1024 + o + 1];
    ((u32*)qD)[t] = pack_rne(c0 - q0, c1 - q1);
}

// ---------------- heavy v2: 2-wave blocks, wB split across waves, LDS-shared A ----
// Block = 128 threads (2 waves), 16 points. Wave w owns output channels
// [w*64, w*64+64) -> wBf[4][4] = 64 VGPRs (half of the old 128). The gathered
// + activated A-tile (16 slots x 128 ch bf16, 4KB) is staged ONCE per point
// into an XOR-swizzled LDS double buffer and consumed by both waves:
//   per point: stage 4KB write + 2 x 4KB read  vs  old per-wave register gather.
// Staging role: slot s = t>>3 (srow = s<15 ? s+1 : 1), granule-pair gp = t&7;
// 8 consecutive lanes cover one 256B row in two contiguous 128B segments.
// Swizzle: granule' = granule ^ (row&7)  (byte ^ ((row&7)<<4)) -> balanced
// banks for both the staging ds_write_b128 and the A-frag ds_read_b128.
// T14 schedule: issue next-point gather loads -> MFMA on current buffer ->
// zpair + ds_write next buffer -> barrier. One barrier per point.
// launch_bounds(128,4): 128-reg cap -> ~4 waves/SIMD (old kernel: 256 regs, 2).
__global__ __launch_bounds__(128, 4) void heavy_kernel(
    const u16* __restrict__ q, const u16* __restrict__ qD,
    const int* __restrict__ nbr, const u16* __restrict__ wBh,
    u16* __restrict__ NEg)
{
    __shared__ uint4 Abuf[2][16][16];      // [buf][slot][granule^swz], 8KB
    const uint4* qv = (const uint4*)q;
    const uint4* qDv = (const uint4*)qD;
    int t = threadIdx.x;
    int w = t >> 6;                        // wave id: output-channel half
    int l = t & 63;
    int quad = l >> 4, l15 = l & 15;

    // persistent wB^T B-fragments for this wave's 64 channels:
    // B[n = w*64 + j*16 + l15][k = kt*32 + quad*8 + jj]
    bf16x8 wBf[4][4];
    #pragma unroll
    for (int j = 0; j < 4; j++)
        #pragma unroll
        for (int kt = 0; kt < 4; kt++) {
            U4 u; u.q = *(const uint4*)(wBh + (w * 64 + j * 16 + l15) * 128 + kt * 32 + quad * 8);
            wBf[j][kt] = u.v;
        }

    int pbase = blockIdx.x * 16;           // 16 points per block, batch-aligned
    int b = pbase >> 16;
    int n0 = pbase & 65535;

    // staging mapping
    int s = t >> 3, gp = t & 7;
    int srow = (s < 15) ? s + 1 : 1;       // slot 15 duplicates neighbor row 1
    const int* nrow = nbr + ((((b << 4) + srow) << 16) + n0);
    int g0 = gp ^ (s & 7);                 // swizzled granule index (low half)
    const uint4* drowBase = qDv + ((size_t)pbase << 4);

    // prologue: stage point 0 into buf 0
    {
        int idx0 = nrow[0];
        const uint4* qrow = qv + ((size_t)((b << 16) | idx0) << 4) + gp;
        const uint4* drow = drowBase + gp;
        uint4 qa = qrow[0], qb = qrow[8];
        uint4 da = drow[0], db = drow[8];
        uint4 fa, fb;
        fa.x = zpair(qa.x, da.x); fa.y = zpair(qa.y, da.y);
        fa.z = zpair(qa.z, da.z); fa.w = zpair(qa.w, da.w);
        fb.x = zpair(qb.x, db.x); fb.y = zpair(qb.y, db.y);
        fb.z = zpair(qb.z, db.z); fb.w = zpair(qb.w, db.w);
        Abuf[0][s][g0] = fa;
        Abuf[0][s][g0 + 8] = fb;
    }
    __syncthreads();

    #pragma unroll 2
    for (int i = 0; i < 16; ++i) {
        // issue next point's gather loads early (consumed after the MFMAs)
        uint4 qa, qb, da, db;
        if (i < 15) {
            int idx = nrow[i + 1];
            const uint4* qrow = qv + ((size_t)((b << 16) | idx) << 4) + gp;
            const uint4* drow = drowBase + ((i + 1) << 4) + gp;
            qa = qrow[0]; qb = qrow[8];
            da = drow[0]; db = drow[8];
        }

        // compute current point from Abuf[i&1]
        f32x4 acc[4];
        #pragma unroll
        for (int j = 0; j < 4; j++) acc[j] = (f32x4){0.f, 0.f, 0.f, 0.f};
        #pragma unroll
        for (int kt = 0; kt < 4; ++kt) {
            U4 a; a.q = Abuf[i & 1][l15][(kt * 4 + quad) ^ (l15 & 7)];
            #pragma unroll
            for (int j = 0; j < 4; ++j)
                acc[j] = __builtin_amdgcn_mfma_f32_16x16x32_bf16(a.v, wBf[j][kt], acc[j], 0, 0, 0);
        }

        // max over 16 slots (rows); fully-coalesced NE store (all 64 lanes)
        float m0 = fmaxf(fmaxf(acc[0][0], acc[0][1]), fmaxf(acc[0][2], acc[0][3]));
        float m1 = fmaxf(fmaxf(acc[1][0], acc[1][1]), fmaxf(acc[1][2], acc[1][3]));
        float m2 = fmaxf(fmaxf(acc[2][0], acc[2][1]), fmaxf(acc[2][2], acc[2][3]));
        float m3 = fmaxf(fmaxf(acc[3][0], acc[3][1]), fmaxf(acc[3][2], acc[3][3]));
        m0 = fmaxf(m0, __shfl_xor(m0, 16, 64)); m0 = fmaxf(m0, __shfl_xor(m0, 32, 64));
        m1 = fmaxf(m1, __shfl_xor(m1, 16, 64)); m1 = fmaxf(m1, __shfl_xor(m1, 32, 64));
        m2 = fmaxf(m2, __shfl_xor(m2, 16, 64)); m2 = fmaxf(m2, __shfl_xor(m2, 32, 64));
        m3 = fmaxf(m3, __shfl_xor(m3, 16, 64)); m3 = fmaxf(m3, __shfl_xor(m3, 32, 64));
        // lane (quad,l15) stores channel w*64 + quad*16 + l15 = w*64 + l
        float msel = (quad == 0) ? m0 : (quad == 1) ? m1 : (quad == 2) ? m2 : m3;
        NEg[(((size_t)(pbase + i)) << 7) + (w << 6) + l] =
            (u16)((__float_as_uint(msel) + 0x8000u) >> 16);

        // stage next point into the other buffer (loads already in flight)
        if (i < 15) {
            uint4 fa, fb;
            fa.x = zpair(qa.x, da.x); fa.y = zpair(qa.y, da.y);
            fa.z = zpair(qa.z, da.z); fa.w = zpair(qa.w, da.w);
            fb.x = zpair(qb.x, db.x); fb.y = zpair(qb.y, db.y);
            fb.z = zpair(qb.z, db.z); fb.w = zpair(qb.w, db.w);
            Abuf[(i + 1) & 1][s][g0] = fa;
            Abuf[(i + 1) & 1][s][g0 + 8] = fb;
        }
        __syncthreads();
    }
}

// ---------------- combine: out = Wcat . [NE; x_bf16; 1; 0] --------------------
__global__ __launch_bounds__(256) void combine_kernel(
    const u16* __restrict__ NEg, const float* __restrict__ x,
    const u16* __restrict__ Wcat, float* __restrict__ out)
{
    __shared__ uint4 NExq[16 * 21];   // per point: 160 bf16 (NE|x|1|0), stride 21 granules
    int tid = threadIdx.x;
    int w = tid >> 6, l = tid & 63;
    int quad = l >> 4, l15 = l & 15;

    // persistent Wcat A-fragments: A[m=o'=w*32+mt*16+l15][k=kt*32+quad*8+j]
    bf16x8 Wcf[2][5];
    #pragma unroll
    for (int mt = 0; mt < 2; mt++)
        #pragma unroll
        for (int kt = 0; kt < 5; kt++) {
            U4 u; u.q = *(const uint4*)(Wcat + (w * 32 + mt * 16 + l15) * 160 + kt * 32 + quad * 8);
            Wcf[mt][kt] = u.v;
        }

    const uint4* NEv = (const uint4*)NEg;
    for (int it = 0; it < 4; ++it) {
        int group = blockIdx.x * 4 + it;        // 8192 groups of 16 points
        int b = group >> 12;
        int n0 = (group & 4095) << 4;
        int p0 = group << 4;
        __syncthreads();   // protect NExq rewrite vs previous readers
        {
            // 256 threads = 16 pts x 16 granules (128 bf16 NE per point)
            int pt = tid >> 4, g = tid & 15;
            NExq[pt * 21 + g] = NEv[((size_t)(p0 + pt) << 4) + g];
        }
        if (tid < 16) {
            int pt = tid;
            float xv[8];
            #pragma unroll
            for (int i = 0; i < 8; i++) xv[i] = x[((b * 8 + i) << 16) + n0 + pt];
            uint4 wx;
            wx.x = pack_rne(xv[0], xv[1]); wx.y = pack_rne(xv[2], xv[3]);
            wx.z = pack_rne(xv[4], xv[5]); wx.w = pack_rne(xv[6], xv[7]);
            NExq[pt * 21 + 16] = wx;
            NExq[pt * 21 + 17] = make_uint4(0x3F80u, 0u, 0u, 0u);
            NExq[pt * 21 + 18] = make_uint4(0u, 0u, 0u, 0u);
            NExq[pt * 21 + 19] = make_uint4(0u, 0u, 0u, 0u);
        }
        __syncthreads();
        f32x4 oa[2];
        oa[0] = (f32x4){0.f, 0.f, 0.f, 0.f};
        oa[1] = (f32x4){0.f, 0.f, 0.f, 0.f};
        #pragma unroll
        for (int kt = 0; kt < 5; ++kt) {
            U4 u; u.q = NExq[l15 * 21 + kt * 4 + quad];
            oa[0] = __builtin_amdgcn_mfma_f32_16x16x32_bf16(Wcf[0][kt], u.v, oa[0], 0, 0, 0);
            oa[1] = __builtin_amdgcn_mfma_f32_16x16x32_bf16(Wcf[1][kt], u.v, oa[1], 0, 0, 0);
        }
        #pragma unroll
        for (int mt = 0; mt < 2; ++mt) {
            int ob = w * 32 + mt * 16 + quad * 4;
            #pragma unroll
            for (int r = 0; r < 4; ++r)
                out[(((b << 7) + ob + r) << 16) + n0 + l15] = oa[mt][r];
        }
    }
}

extern "C" void kernel_launch(void* const* d_in, const int* in_sizes, int n_in,
                              void* d_out, int out_size, void* d_ws, size_t ws_size,
                              hipStream_t stream) {
    const float* x   = (const float*)d_in[0];
    const int*   nbr = (const int*)d_in[1];
    const float* g1  = (const float*)d_in[2];
    const float* b1  = (const float*)d_in[3];
    const float* m1  = (const float*)d_in[4];
    const float* v1  = (const float*)d_in[5];
    const float* w1  = (const float*)d_in[6];
    const float* c1b = (const float*)d_in[7];
    const float* g2  = (const float*)d_in[8];
    const float* b2  = (const float*)d_in[9];
    const float* m2  = (const float*)d_in[10];
    const float* v2  = (const float*)d_in[11];
    const float* wA  = (const float*)d_in[12];
    const float* g3  = (const float*)d_in[13];
    const float* b3  = (const float*)d_in[14];
    const float* m3  = (const float*)d_in[15];
    const float* v3  = (const float*)d_in[16];
    const float* wB  = (const float*)d_in[17];
    const float* wf  = (const float*)d_in[18];
    const float* bfv = (const float*)d_in[19];

    float* wsF  = (float*)d_ws;
    u16*   wBh  = (u16*)((char*)d_ws + WS_WB);
    u16*   Wcat = (u16*)((char*)d_ws + WS_WCAT);
    u16*   q    = (u16*)((char*)d_ws + WS_Q);
    u16*   qD   = (u16*)((char*)d_ws + WS_QD);
    u16*   NEg  = (u16*)((char*)d_ws + WS_NE);
    float* out  = (float*)d_out;

    prep_kernel<<<1, 256, 0, stream>>>(g1, b1, m1, v1, w1, c1b, g2, b2, m2, v2,
                                       wA, g3, b3, m3, v3, wB, wf, bfv, wsF, wBh, Wcat);
    q_kernel<<<32768, 256, 0, stream>>>(x, wsF, q, qD);
    heavy_kernel<<<8192, 128, 0, stream>>>(q, qD, nbr, wBh, NEg);
    combine_kernel<<<2048, 256, 0, stream>>>(NEg, x, Wcat, out);
}

// Round 2
// 300.753 us; speedup vs baseline: 1.1736x; 1.0371x over previous
//
#include <hip/hip_runtime.h>
#include <hip/hip_bf16.h>

typedef unsigned short u16;
typedef unsigned int u32;
typedef short bf16x8 __attribute__((ext_vector_type(8)));
typedef float f32x4 __attribute__((ext_vector_type(4)));

#define EPSV 1e-5f
// ws byte layout
#define WS_A3    0                       // 128*8 f32
#define WS_C3    4096                    // 128 f32
#define WS_WB    4608                    // 128*128 bf16
#define WS_WCAT  37376                   // 128*160 bf16 [wf2 | A1 | bias | 0]
#define WS_Q     78336                   // 33.55 MB bf16 q = A3@x
#define WS_QD    (78336 + 33554432)      // 33.55 MB bf16 qD = c3 - q
#define WS_NE    (78336 + 2*33554432)    // 33.55 MB bf16 NE

union U4 { uint4 q; bf16x8 v; };

__device__ __forceinline__ u16 f2bf(float f) {
    union { __hip_bfloat16 h; u16 u; } cv;
    cv.h = __float2bfloat16(f);
    return cv.u;
}
__device__ __forceinline__ u32 pack_rne(float a, float b) {
    u32 ua = __float_as_uint(a), ub = __float_as_uint(b);
    ua = ua + 0x7FFFu + ((ua >> 16) & 1u);
    ub = ub + 0x7FFFu + ((ub >> 16) & 1u);
    return (ua >> 16) | (ub & 0xFFFF0000u);
}
// z = relu(bf(a_half) + bf(d_half)), packed bf16 via v_cvt_pk_bf16_f32 (RNE)
__device__ __forceinline__ u32 zpair(u32 a, u32 d) {
    float lo = fmaxf(__uint_as_float(a << 16) + __uint_as_float(d << 16), 0.f);
    float hi = fmaxf(__uint_as_float(a & 0xFFFF0000u) + __uint_as_float(d & 0xFFFF0000u), 0.f);
    u32 r;
    asm("v_cvt_pk_bf16_f32 %0, %1, %2" : "=v"(r) : "v"(lo), "v"(hi));
    return r;
}

// ---------------- prep: fold constants (fully parallel, LDS-staged) ----------------
__global__ __launch_bounds__(256) void prep_kernel(
    const float* g1, const float* b1, const float* m1, const float* v1,
    const float* w1, const float* c1b,
    const float* g2, const float* b2, const float* m2, const float* v2,
    const float* wA,
    const float* g3, const float* b3, const float* m3, const float* v3,
    const float* wB, const float* wf, const float* bfv,
    float* ws, u16* wBh, u16* Wc)
{
    __shared__ float wfL[16384];     // wf left half, 64 KB
    __shared__ float w1s[1024];
    __shared__ float c1s[128];
    __shared__ float s1[8], be1[8], s2[8], be2[8];
    __shared__ float w1fS[128][8];
    __shared__ float cbS[128];
    int t = threadIdx.x;

    // stage (coalesced, latency-pipelined across 256 threads)
    for (int i = t; i < 16384; i += 256) wfL[i] = wf[((i >> 7) << 8) + (i & 127)];
    for (int i = t; i < 1024; i += 256) w1s[i] = w1[i];
    if (t < 128) c1s[t] = c1b[t];
    if (t < 8) {
        float s = g1[t] * rsqrtf(v1[t] + EPSV); s1[t] = s; be1[t] = b1[t] - m1[t] * s;
        float u = g2[t] * rsqrtf(v2[t] + EPSV); s2[t] = u; be2[t] = b2[t] - m2[t] * u;
    }
    __syncthreads();

    // fold wf_left @ [w1 | c1b]: thread (o, half) does 4 i's (+ cb on half 1)
    {
        int o = t >> 1, half = t & 1;
        float a0 = 0.f, a1 = 0.f, a2 = 0.f, a3 = 0.f, cb = 0.f;
        const float* wro = wfL + o * 128;
        int i0 = half * 4;
        for (int c = 0; c < 128; c++) {
            float f = wro[c];
            const float* wr = w1s + c * 8 + i0;
            a0 += f * wr[0]; a1 += f * wr[1]; a2 += f * wr[2]; a3 += f * wr[3];
            if (half) cb += f * c1s[c];
        }
        w1fS[o][i0] = a0; w1fS[o][i0 + 1] = a1; w1fS[o][i0 + 2] = a2; w1fS[o][i0 + 3] = a3;
        if (half) cbS[o] = cb;
    }
    __syncthreads();

    if (t < 128) {
        int o = t;
        float s3 = g3[o] * rsqrtf(v3[o] + EPSV);
        float be3 = b3[o] - m3[o] * s3;
        float* A3 = ws;
        float* c3 = ws + 1024;
        float csum = 0.f;
        #pragma unroll
        for (int i = 0; i < 8; i++) {
            float w = wA[o * 8 + i];
            A3[o * 8 + i] = s3 * w * s2[i] * s1[i];
            csum += w * be2[i];
        }
        c3[o] = s3 * csum + be3;

        float bs = bfv[o] + cbS[o];
        #pragma unroll
        for (int i = 0; i < 8; i++) {
            float w1f = w1fS[o][i];
            bs += w1f * be1[i];
            Wc[o * 160 + 128 + i] = f2bf(w1f * s1[i]);
        }
        Wc[o * 160 + 136] = f2bf(bs);
        for (int k = 137; k < 160; k++) Wc[o * 160 + k] = 0;
    }
    // Wcat wf2 block: 16384 elems, coalesced grid-stride
    for (int j = t; j < 16384; j += 256) {
        int o = j >> 7, c = j & 127;
        Wc[o * 160 + c] = f2bf(wf[o * 256 + 128 + c]);
    }
    // wB cast: 8192 packed u32, coalesced
    {
        u32* wbo = (u32*)wBh;
        for (int j = t; j < 8192; j += 256)
            wbo[j] = pack_rne(wB[2 * j], wB[2 * j + 1]);
    }
}

// ---------------- q = A3 @ x (bf16) and qD = c3 - q (bf16) --------------------
__global__ __launch_bounds__(256) void q_kernel(const float* __restrict__ x,
                                                const float* __restrict__ ws,
                                                u16* __restrict__ q,
                                                u16* __restrict__ qD)
{
    int t = blockIdx.x * 256 + threadIdx.x;
    int pt = t >> 6;
    int o = (t & 63) * 2;
    int b = pt >> 16, n = pt & 65535;
    const float* A3 = ws;
    float xv[8];
    #pragma unroll
    for (int i = 0; i < 8; i++) xv[i] = x[(((b << 3) + i) << 16) | n];
    float q0 = 0.f, q1 = 0.f;
    #pragma unroll
    for (int i = 0; i < 8; i++) {
        q0 += A3[o * 8 + i] * xv[i];
        q1 += A3[(o + 1) * 8 + i] * xv[i];
    }
    ((u32*)q)[t] = pack_rne(q0, q1);
    float c0 = ws[1024 + o], c1 = ws[1024 + o + 1];
    ((u32*)qD)[t] = pack_rne(c0 - q0, c1 - q1);
}

// ---------------- heavy v3: 4-wave blocks, 32 ch/wave, depth-2 gather pipeline ----
// Block = 256 threads (4 waves), 16 points. Wave w owns output channels
// [w*32, w*32+32) -> wBf[2][4] = 32 VGPRs, acc = 8. The gathered+activated
// A-tile (16 slots x 128 ch bf16, 4KB) is staged once per point into an
// XOR-swizzled LDS double buffer and consumed by all 4 waves.
// Staging: thread (s = t>>4, gp = t&15) stages ONE uint4 (4 zpairs).
// Depth-2 software pipeline: two in-flight load sets {q,d} (pt p in SET_{p&1}),
// idx prefetched 3 points ahead -> load->use span ~2 iterations (hides the
// ~600cy random-gather latency that R1's depth-1 schedule exposed).
// launch_bounds(256,6): cap ~85 unified regs -> ~6 waves/SIMD (R1 was ~3.2).
#define HSTEP(I, QN, DN, QC, DC)                                              \
    {                                                                         \
        QN = qb[(u32)((idxR << 4) | gp)];                                     \
        DN = db[((((I) + 2) & 15) << 4) + gp];                                \
        idxR = nb0[nvoff + (((I) + 3) & 15)];                                 \
        f32x4 acc0 = {0.f, 0.f, 0.f, 0.f}, acc1 = {0.f, 0.f, 0.f, 0.f};       \
        _Pragma("unroll")                                                     \
        for (int kt = 0; kt < 4; ++kt) {                                      \
            U4 a; a.q = Abuf[(I) & 1][l15][(kt * 4 + quad) ^ (l15 & 7)];      \
            acc0 = __builtin_amdgcn_mfma_f32_16x16x32_bf16(a.v, wBf[0][kt], acc0, 0, 0, 0); \
            acc1 = __builtin_amdgcn_mfma_f32_16x16x32_bf16(a.v, wBf[1][kt], acc1, 0, 0, 0); \
        }                                                                     \
        float m0 = fmaxf(fmaxf(fmaxf(acc0[0], acc0[1]), acc0[2]), acc0[3]);   \
        float m1 = fmaxf(fmaxf(fmaxf(acc1[0], acc1[1]), acc1[2]), acc1[3]);   \
        m0 = fmaxf(m0, __shfl_xor(m0, 16, 64));                               \
        m0 = fmaxf(m0, __shfl_xor(m0, 32, 64));                               \
        m1 = fmaxf(m1, __shfl_xor(m1, 16, 64));                               \
        m1 = fmaxf(m1, __shfl_xor(m1, 32, 64));                               \
        if (l < 32)                                                           \
            NEg[((size_t)(pbase + (I)) << 7) + (w << 5) + l] =                \
                (u16)((__float_as_uint((quad == 0) ? m0 : m1) + 0x8000u) >> 16); \
        uint4 f;                                                              \
        f.x = zpair(QC.x, DC.x); f.y = zpair(QC.y, DC.y);                     \
        f.z = zpair(QC.z, DC.z); f.w = zpair(QC.w, DC.w);                     \
        Abuf[((I) + 1) & 1][s][g0] = f;                                       \
        __syncthreads();                                                      \
    }

__global__ __launch_bounds__(256, 6) void heavy_kernel(
    const u16* __restrict__ q, const u16* __restrict__ qD,
    const int* __restrict__ nbr, const u16* __restrict__ wBh,
    u16* __restrict__ NEg)
{
    __shared__ uint4 Abuf[2][16][16];      // [buf][slot][granule^swz], 8KB
    const uint4* qv = (const uint4*)q;
    const uint4* qDv = (const uint4*)qD;
    int t = threadIdx.x;
    int w = t >> 6;                        // wave id: 32-channel group
    int l = t & 63;
    int quad = l >> 4, l15 = l & 15;

    // persistent wB^T B-fragments for this wave's 32 channels:
    // B[n = w*32 + j*16 + l15][k = kt*32 + quad*8 + jj]
    bf16x8 wBf[2][4];
    #pragma unroll
    for (int j = 0; j < 2; j++)
        #pragma unroll
        for (int kt = 0; kt < 4; kt++) {
            U4 u; u.q = *(const uint4*)(wBh + (w * 32 + j * 16 + l15) * 128 + kt * 32 + quad * 8);
            wBf[j][kt] = u.v;
        }

    int pbase = blockIdx.x * 16;           // 16 points per block, batch-aligned
    int b = pbase >> 16;
    int n0 = pbase & 65535;

    // staging mapping: thread stages one uint4 (8 bf16 ch) of one slot
    int s = t >> 4, gp = t & 15;
    int srow = (s < 15) ? s + 1 : 1;       // slot 15 duplicates neighbor row 1
    const int* nb0 = nbr + ((size_t)b << 20);        // + b*16*65536
    int nvoff = (srow << 16) + n0;                   // 32-bit elem offset
    const uint4* qb = qv + ((size_t)b << 20);        // + b*65536 rows *16
    const uint4* db = qDv + ((size_t)pbase << 4);    // center rows base
    int g0 = gp ^ (s & 7);                 // swizzled granule index

    // prologue: issue pt0,pt1 loads; idx 2 ahead; stage pt0 -> buf0
    int idxR;
    uint4 qS0, dS0, qS1, dS1;
    {
        int idx0 = nb0[nvoff];
        qS0 = qb[(u32)((idx0 << 4) | gp)];
        dS0 = db[gp];
        int idx1 = nb0[nvoff + 1];
        qS1 = qb[(u32)((idx1 << 4) | gp)];
        dS1 = db[16 + gp];
        idxR = nb0[nvoff + 2];
        uint4 f;
        f.x = zpair(qS0.x, dS0.x); f.y = zpair(qS0.y, dS0.y);
        f.z = zpair(qS0.z, dS0.z); f.w = zpair(qS0.w, dS0.w);
        Abuf[0][s][g0] = f;
    }
    __syncthreads();

    for (int i = 0; i < 16; i += 2) {
        HSTEP(i,     qS0, dS0, qS1, dS1)   // issue pt i+2 -> S0, consume S1 (pt i+1)
        HSTEP(i + 1, qS1, dS1, qS0, dS0)   // issue pt i+3 -> S1, consume S0 (pt i+2)
    }
}

// ---------------- combine: out = Wcat . [NE; x_bf16; 1; 0] --------------------
__global__ __launch_bounds__(256) void combine_kernel(
    const u16* __restrict__ NEg, const float* __restrict__ x,
    const u16* __restrict__ Wcat, float* __restrict__ out)
{
    __shared__ uint4 NExq[16 * 21];   // per point: 160 bf16 (NE|x|1|0), stride 21 granules
    int tid = threadIdx.x;
    int w = tid >> 6, l = tid & 63;
    int quad = l >> 4, l15 = l & 15;

    // persistent Wcat A-fragments: A[m=o'=w*32+mt*16+l15][k=kt*32+quad*8+j]
    bf16x8 Wcf[2][5];
    #pragma unroll
    for (int mt = 0; mt < 2; mt++)
        #pragma unroll
        for (int kt = 0; kt < 5; kt++) {
            U4 u; u.q = *(const uint4*)(Wcat + (w * 32 + mt * 16 + l15) * 160 + kt * 32 + quad * 8);
            Wcf[mt][kt] = u.v;
        }

    const uint4* NEv = (const uint4*)NEg;
    for (int it = 0; it < 4; ++it) {
        int group = blockIdx.x * 4 + it;        // 8192 groups of 16 points
        int b = group >> 12;
        int n0 = (group & 4095) << 4;
        int p0 = group << 4;
        __syncthreads();   // protect NExq rewrite vs previous readers
        {
            // 256 threads = 16 pts x 16 granules (128 bf16 NE per point)
            int pt = tid >> 4, g = tid & 15;
            NExq[pt * 21 + g] = NEv[((size_t)(p0 + pt) << 4) + g];
        }
        if (tid < 64) {
            // 64 threads: pt = tid>>2, pair pr = tid&3 -> 2 x-scalars each
            int pt = tid >> 2, pr = tid & 3;
            float xa = x[((b * 8 + 2 * pr) << 16) + n0 + pt];
            float xb = x[((b * 8 + 2 * pr + 1) << 16) + n0 + pt];
            ((u32*)&NExq[pt * 21 + 16])[pr] = pack_rne(xa, xb);
            if (pr == 0) {
                NExq[pt * 21 + 17] = make_uint4(0x3F80u, 0u, 0u, 0u);
                NExq[pt * 21 + 18] = make_uint4(0u, 0u, 0u, 0u);
                NExq[pt * 21 + 19] = make_uint4(0u, 0u, 0u, 0u);
            }
        }
        __syncthreads();
        f32x4 oa[2];
        oa[0] = (f32x4){0.f, 0.f, 0.f, 0.f};
        oa[1] = (f32x4){0.f, 0.f, 0.f, 0.f};
        #pragma unroll
        for (int kt = 0; kt < 5; ++kt) {
            U4 u; u.q = NExq[l15 * 21 + kt * 4 + quad];
            oa[0] = __builtin_amdgcn_mfma_f32_16x16x32_bf16(Wcf[0][kt], u.v, oa[0], 0, 0, 0);
            oa[1] = __builtin_amdgcn_mfma_f32_16x16x32_bf16(Wcf[1][kt], u.v, oa[1], 0, 0, 0);
        }
        #pragma unroll
        for (int mt = 0; mt < 2; ++mt) {
            int ob = w * 32 + mt * 16 + quad * 4;
            #pragma unroll
            for (int r = 0; r < 4; ++r)
                out[(((b << 7) + ob + r) << 16) + n0 + l15] = oa[mt][r];
        }
    }
}

extern "C" void kernel_launch(void* const* d_in, const int* in_sizes, int n_in,
                              void* d_out, int out_size, void* d_ws, size_t ws_size,
                              hipStream_t stream) {
    const float* x   = (const float*)d_in[0];
    const int*   nbr = (const int*)d_in[1];
    const float* g1  = (const float*)d_in[2];
    const float* b1  = (const float*)d_in[3];
    const float* m1  = (const float*)d_in[4];
    const float* v1  = (const float*)d_in[5];
    const float* w1  = (const float*)d_in[6];
    const float* c1b = (const float*)d_in[7];
    const float* g2  = (const float*)d_in[8];
    const float* b2  = (const float*)d_in[9];
    const float* m2  = (const float*)d_in[10];
    const float* v2  = (const float*)d_in[11];
    const float* wA  = (const float*)d_in[12];
    const float* g3  = (const float*)d_in[13];
    const float* b3  = (const float*)d_in[14];
    const float* m3  = (const float*)d_in[15];
    const float* v3  = (const float*)d_in[16];
    const float* wB  = (const float*)d_in[17];
    const float* wf  = (const float*)d_in[18];
    const float* bfv = (const float*)d_in[19];

    float* wsF  = (float*)d_ws;
    u16*   wBh  = (u16*)((char*)d_ws + WS_WB);
    u16*   Wcat = (u16*)((char*)d_ws + WS_WCAT);
    u16*   q    = (u16*)((char*)d_ws + WS_Q);
    u16*   qD   = (u16*)((char*)d_ws + WS_QD);
    u16*   NEg  = (u16*)((char*)d_ws + WS_NE);
    float* out  = (float*)d_out;

    prep_kernel<<<1, 256, 0, stream>>>(g1, b1, m1, v1, w1, c1b, g2, b2, m2, v2,
                                       wA, g3, b3, m3, v3, wB, wf, bfv, wsF, wBh, Wcat);
    q_kernel<<<32768, 256, 0, stream>>>(x, wsF, q, qD);
    heavy_kernel<<<8192, 256, 0, stream>>>(q, qD, nbr, wBh, NEg);
    combine_kernel<<<2048, 256, 0, stream>>>(NEg, x, Wcat, out);
}